// Round 3
// baseline (1141.760 us; speedup 1.0000x reference)
//
#include <hip/hip_runtime.h>

// MCLLoss: masked L1 loss over 5 overlapping value-ranges of real_img.
// Ranges: (-1,1), (-1,-.5), (-.5,0), (0,.5), (.5,1) — inclusive bounds,
// masks overlap; class_mask takes the LAST matching range index.
// Output layout: [loss, losses[5], class_mask_rescaled[N]]; rescale = cls*0.5-1.
//
// R8: single fused kernel (last-block pattern), R5 main-loop shape.
//  - R6/R7 post-mortem: batching 8 pairs/thread regressed (VGPR=24 => compiler
//    serialized the batches into 4 memory round-trips; R5's all-loads-upfront
//    one-round-trip shape with 4x more waves hides latency better). Reverted.
//  - Nontemporal stores: measured neutral-to-negative (FETCH unchanged). Dropped.
//  - Kept from R6: 256 atomic banks (chain depth 32, was 128) and counts
//    carried as floats (exact: integer-valued < 2^24) for one 10-value path.
//  - NEW: mcl_final fused via ticket counter; the last block reduces the 256
//    banks with agent-scope loads while still hot. Removes one kernel node and
//    the cold cross-XCD read chain of the old single-block final kernel.

#define N_BANKS 256
#define BANK_F  16   // floats per bank (64B line): sums [0..4], counts-as-float [5..9]
#define TPB     256

__device__ __forceinline__ void proc_elem(float pv, float rv,
                                          float s[5], float c[5], float& ov)
{
    float d = fabsf(pv - rv);
    bool geM1  = rv >= -1.0f;
    bool leM05 = rv <= -0.5f;
    bool geM05 = rv >= -0.5f;
    bool le0   = rv <=  0.0f;
    bool ge0   = rv >=  0.0f;
    bool le05  = rv <=  0.5f;
    bool ge05  = rv >=  0.5f;
    bool le1   = rv <=  1.0f;
    bool in0 = geM1  && le1;
    bool in1 = geM1  && leM05;
    bool in2 = geM05 && le0;
    bool in3 = ge0   && le05;
    bool in4 = ge05  && le1;
    s[0] += in0 ? d : 0.f;  c[0] += in0 ? 1.f : 0.f;
    s[1] += in1 ? d : 0.f;  c[1] += in1 ? 1.f : 0.f;
    s[2] += in2 ? d : 0.f;  c[2] += in2 ? 1.f : 0.f;
    s[3] += in3 ? d : 0.f;  c[3] += in3 ? 1.f : 0.f;
    s[4] += in4 ? d : 0.f;  c[4] += in4 ? 1.f : 0.f;
    // class value directly as float: -1, -.5, 0, .5, 1 (last matching wins)
    ov = in4 ? 1.0f : (in3 ? 0.5f : (in2 ? 0.0f : (in1 ? -0.5f : -1.0f)));
}

__device__ __forceinline__ void proc_group(int i, const float4& p, const float4& r,
                                           float s[5], float c[5],
                                           float* __restrict__ mask_out)
{
    float ov0, ov1, ov2, ov3;
    proc_elem(p.x, r.x, s, c, ov0);
    proc_elem(p.y, r.y, s, c, ov1);
    proc_elem(p.z, r.z, s, c, ov2);
    proc_elem(p.w, r.w, s, c, ov3);
    // mask_out = out+6: 8-byte aligned only -> float2 stores
    float2* mo = (float2*)(mask_out + 4 * (size_t)i);
    mo[0] = make_float2(ov0, ov1);
    mo[1] = make_float2(ov2, ov3);
}

__global__ __launch_bounds__(TPB, 8) void mcl_fused(
    const float* __restrict__ pre, const float* __restrict__ real,
    float* __restrict__ out, float* __restrict__ acc,
    unsigned int* __restrict__ ticket, int n4, int n, int nblocks)
{
    float* mask_out = out + 6;
    float s[5] = {0.f, 0.f, 0.f, 0.f, 0.f};
    float c[5] = {0.f, 0.f, 0.f, 0.f, 0.f};

    const int t = threadIdx.x;
    const int i0 = blockIdx.x * 512 + t;   // block covers 512 float4 (8 KB)
    const int i1 = i0 + 256;
    const bool v0 = i0 < n4;
    const bool v1 = i1 < n4;

    const float4* pre4  = (const float4*)pre;
    const float4* real4 = (const float4*)real;

    // all four 16B loads upfront: one memory round-trip per thread, 64B in
    // flight for the block's whole life (R5 shape — proven fastest)
    float4 p0, r0, p1, r1;
    if (v0) { p0 = pre4[i0]; r0 = real4[i0]; }
    if (v1) { p1 = pre4[i1]; r1 = real4[i1]; }

    if (v0) proc_group(i0, p0, r0, s, c, mask_out);
    if (v1) proc_group(i1, p1, r1, s, c, mask_out);

    // scalar tail (n not divisible by 4)
    {
        int tail_base = n4 * 4;
        int tail = n - tail_base;
        int gtid = blockIdx.x * TPB + t;
        if (gtid < tail) {
            int idx = tail_base + gtid;
            float ov;
            proc_elem(pre[idx], real[idx], s, c, ov);
            mask_out[idx] = ov;
        }
    }

    // wave64 butterfly reduction (10 floats)
#pragma unroll
    for (int j = 0; j < 5; ++j) {
#pragma unroll
        for (int off = 32; off > 0; off >>= 1) {
            s[j] += __shfl_down(s[j], off, 64);
            c[j] += __shfl_down(c[j], off, 64);
        }
    }

    __shared__ float ls[4][5];
    __shared__ float lc[4][5];
    const int lane = t & 63;
    const int wave = t >> 6;
    if (lane == 0) {
#pragma unroll
        for (int j = 0; j < 5; ++j) { ls[wave][j] = s[j]; lc[wave][j] = c[j]; }
    }
    __syncthreads();

    // 10 lanes, one atomic each; 8192 blocks over 256 banks -> chain depth 32
    if (t < 10) {
        int j = (t < 5) ? t : t - 5;
        float v = (t < 5) ? (ls[0][j] + ls[1][j] + ls[2][j] + ls[3][j])
                          : (lc[0][j] + lc[1][j] + lc[2][j] + lc[3][j]);
        float* bank = acc + (size_t)(blockIdx.x & (N_BANKS - 1)) * BANK_F;
        atomicAdd(&bank[t], v);   // sums at [0..4], counts at [5..9]
    }

    // ---- last-block final reduction (canonical threadfence-reduction pattern)
    __threadfence();              // make this block's bank adds device-visible
    __shared__ unsigned int lastflag;
    __syncthreads();
    if (t == 0)
        lastflag = (atomicAdd(ticket, 1u) == (unsigned)(nblocks - 1)) ? 1u : 0u;
    __syncthreads();
    if (lastflag) {
        __threadfence();          // acquire side
        // thread t owns bank t: 10 agent-scope loads (bypass possibly-stale L1/L2 copies)
        float v[10];
        const float* bank = acc + (size_t)t * BANK_F;
#pragma unroll
        for (int j = 0; j < 10; ++j)
            v[j] = __hip_atomic_load(&bank[j], __ATOMIC_RELAXED, __HIP_MEMORY_SCOPE_AGENT);
        // reduce 256 threads -> 1: wave butterfly, then cross-wave fold in LDS
#pragma unroll
        for (int j = 0; j < 10; ++j) {
#pragma unroll
            for (int off = 32; off > 0; off >>= 1)
                v[j] += __shfl_down(v[j], off, 64);
        }
        __shared__ float fs[4][10];
        if (lane == 0) {
#pragma unroll
            for (int j = 0; j < 10; ++j) fs[wave][j] = v[j];
        }
        __syncthreads();
        if (t == 0) {
            float total = 0.f;
#pragma unroll
            for (int j = 0; j < 5; ++j) {
                float ssum = fs[0][j] + fs[1][j] + fs[2][j] + fs[3][j];
                float csum = fs[0][5 + j] + fs[1][5 + j] + fs[2][5 + j] + fs[3][5 + j];
                float denom = csum > 1.f ? csum : 1.f;     // max(count, 1)
                float lv = (csum == 0.f) ? 0.f : (ssum / denom) * 0.2f;
                out[1 + j] = lv;
                total += lv;
            }
            out[0] = total;
        }
    }
}

extern "C" void kernel_launch(void* const* d_in, const int* in_sizes, int n_in,
                              void* d_out, int out_size, void* d_ws, size_t ws_size,
                              hipStream_t stream) {
    const float* pre  = (const float*)d_in[0];
    const float* real = (const float*)d_in[1];
    float* out = (float*)d_out;
    int n = in_sizes[0];
    int n4 = n / 4;

    float* acc = (float*)d_ws;                     // 256 banks x 16 floats = 16 KB
    unsigned int* ticket = (unsigned int*)(acc + N_BANKS * BANK_F);

    // d_ws re-poisoned to 0xAA before every timed call — zero banks + ticket.
    (void)hipMemsetAsync(d_ws, 0,
                         N_BANKS * BANK_F * sizeof(float) + sizeof(unsigned int),
                         stream);

    int blocks = (n4 + 511) / 512;                 // 8192 for N=16M
    if (blocks < 1) blocks = 1;
    mcl_fused<<<blocks, TPB, 0, stream>>>(pre, real, out, acc, ticket, n4, n, blocks);
}

// Round 4
// 181.695 us; speedup vs baseline: 6.2839x; 6.2839x over previous
//
#include <hip/hip_runtime.h>

// MCLLoss: masked L1 loss over 5 overlapping value-ranges of real_img.
// Ranges: (-1,1), (-1,-.5), (-.5,0), (0,.5), (.5,1) — inclusive bounds,
// masks overlap; class_mask takes the LAST matching range index.
// Output layout: [loss, losses[5], class_mask_rescaled[N]]; rescale = cls*0.5-1.
//
// R9: 2-node graph, zero atomics, zero fences.
//  - R8 post-mortem: fused last-block pattern = 1055us. __threadfence() per
//    block forces a device-scope ordering of ALL prior writes (incl. the 8KB
//    mask stores in the non-coherent per-XCD L2) -> per-block L2 writeback,
//    8192x serialized. Fusion abandoned; fences are per-block structural cost.
//  - Node-count ledger: R5/R7 (3 nodes) total-main ~= 112us; R8 (2 nodes)
//    ~= 86us -> ~40us/node. So: drop the memset node. Blocks plain-store
//    their 10 partials into private SoA slots (acc[j*nblocks+bid]) — no
//    zero-init required, no atomic chains, no RMW stall at block exit.
//  - Final kernel parallelized: 1024 threads, coalesced SoA read of the 10
//    planes (320KB), tree reduce. Replaces the cold 64-thread bank walk.
//  - Main loop = R5 shape (proven 63us): 8192 blocks x 2 float4-pairs, all
//    four 16B loads upfront (one memory round-trip/thread), plain float2
//    mask stores. Counts as floats (exact: integer-valued < 2^24).

#define TPB 256

__device__ __forceinline__ void proc_elem(float pv, float rv,
                                          float s[5], float c[5], float& ov)
{
    float d = fabsf(pv - rv);
    bool geM1  = rv >= -1.0f;
    bool leM05 = rv <= -0.5f;
    bool geM05 = rv >= -0.5f;
    bool le0   = rv <=  0.0f;
    bool ge0   = rv >=  0.0f;
    bool le05  = rv <=  0.5f;
    bool ge05  = rv >=  0.5f;
    bool le1   = rv <=  1.0f;
    bool in0 = geM1  && le1;
    bool in1 = geM1  && leM05;
    bool in2 = geM05 && le0;
    bool in3 = ge0   && le05;
    bool in4 = ge05  && le1;
    s[0] += in0 ? d : 0.f;  c[0] += in0 ? 1.f : 0.f;
    s[1] += in1 ? d : 0.f;  c[1] += in1 ? 1.f : 0.f;
    s[2] += in2 ? d : 0.f;  c[2] += in2 ? 1.f : 0.f;
    s[3] += in3 ? d : 0.f;  c[3] += in3 ? 1.f : 0.f;
    s[4] += in4 ? d : 0.f;  c[4] += in4 ? 1.f : 0.f;
    // class value directly as float: -1, -.5, 0, .5, 1 (last matching wins)
    ov = in4 ? 1.0f : (in3 ? 0.5f : (in2 ? 0.0f : (in1 ? -0.5f : -1.0f)));
}

__device__ __forceinline__ void proc_group(int i, const float4& p, const float4& r,
                                           float s[5], float c[5],
                                           float* __restrict__ mask_out)
{
    float ov0, ov1, ov2, ov3;
    proc_elem(p.x, r.x, s, c, ov0);
    proc_elem(p.y, r.y, s, c, ov1);
    proc_elem(p.z, r.z, s, c, ov2);
    proc_elem(p.w, r.w, s, c, ov3);
    // mask_out = out+6: 8-byte aligned only -> float2 stores
    float2* mo = (float2*)(mask_out + 4 * (size_t)i);
    mo[0] = make_float2(ov0, ov1);
    mo[1] = make_float2(ov2, ov3);
}

__global__ __launch_bounds__(TPB, 8) void mcl_main(
    const float* __restrict__ pre, const float* __restrict__ real,
    float* __restrict__ mask_out, float* __restrict__ acc, int n4, int n)
{
    float s[5] = {0.f, 0.f, 0.f, 0.f, 0.f};
    float c[5] = {0.f, 0.f, 0.f, 0.f, 0.f};

    const int t = threadIdx.x;
    const int i0 = blockIdx.x * 512 + t;   // block covers 512 float4 (8 KB)
    const int i1 = i0 + 256;
    const bool v0 = i0 < n4;
    const bool v1 = i1 < n4;

    const float4* pre4  = (const float4*)pre;
    const float4* real4 = (const float4*)real;

    // all four 16B loads upfront: one memory round-trip per thread, 64B in
    // flight for the block's whole life (R5 shape — proven fastest)
    float4 p0, r0, p1, r1;
    if (v0) { p0 = pre4[i0]; r0 = real4[i0]; }
    if (v1) { p1 = pre4[i1]; r1 = real4[i1]; }

    if (v0) proc_group(i0, p0, r0, s, c, mask_out);
    if (v1) proc_group(i1, p1, r1, s, c, mask_out);

    // scalar tail (n not divisible by 4)
    {
        int tail_base = n4 * 4;
        int tail = n - tail_base;
        int gtid = blockIdx.x * TPB + t;
        if (gtid < tail) {
            int idx = tail_base + gtid;
            float ov;
            proc_elem(pre[idx], real[idx], s, c, ov);
            mask_out[idx] = ov;
        }
    }

    // wave64 butterfly reduction (10 floats)
#pragma unroll
    for (int j = 0; j < 5; ++j) {
#pragma unroll
        for (int off = 32; off > 0; off >>= 1) {
            s[j] += __shfl_down(s[j], off, 64);
            c[j] += __shfl_down(c[j], off, 64);
        }
    }

    __shared__ float ls[4][5];
    __shared__ float lc[4][5];
    const int lane = t & 63;
    const int wave = t >> 6;
    if (lane == 0) {
#pragma unroll
        for (int j = 0; j < 5; ++j) { ls[wave][j] = s[j]; lc[wave][j] = c[j]; }
    }
    __syncthreads();

    // plain store of 10 partials into this block's private SoA slots.
    // No atomics, no zero-init dependency: final reads exactly what's written.
    if (t < 10) {
        int j = (t < 5) ? t : t - 5;
        float v = (t < 5) ? (ls[0][j] + ls[1][j] + ls[2][j] + ls[3][j])
                          : (lc[0][j] + lc[1][j] + lc[2][j] + lc[3][j]);
        acc[(size_t)t * gridDim.x + blockIdx.x] = v;
    }
}

__global__ __launch_bounds__(1024) void mcl_final(
    const float* __restrict__ acc, float* __restrict__ out, int nblocks)
{
    const int t = threadIdx.x;
    float sum[10];
#pragma unroll
    for (int j = 0; j < 10; ++j) sum[j] = 0.f;

    // coalesced SoA read: plane j is nblocks contiguous floats
    for (int slot = t; slot < nblocks; slot += 1024) {
#pragma unroll
        for (int j = 0; j < 10; ++j)
            sum[j] += acc[(size_t)j * nblocks + slot];
    }

    // wave butterfly
#pragma unroll
    for (int j = 0; j < 10; ++j) {
#pragma unroll
        for (int off = 32; off > 0; off >>= 1)
            sum[j] += __shfl_down(sum[j], off, 64);
    }

    __shared__ float fs[16][10];
    const int lane = t & 63;
    const int wave = t >> 6;
    if (lane == 0) {
#pragma unroll
        for (int j = 0; j < 10; ++j) fs[wave][j] = sum[j];
    }
    __syncthreads();

    __shared__ float red[10];
    if (t < 10) {
        float v = 0.f;
#pragma unroll
        for (int w = 0; w < 16; ++w) v += fs[w][t];
        red[t] = v;
    }
    __syncthreads();

    if (t == 0) {
        float total = 0.f;
#pragma unroll
        for (int j = 0; j < 5; ++j) {
            float ssum = red[j];
            float csum = red[5 + j];                  // exact integer-valued float
            float denom = csum > 1.f ? csum : 1.f;    // max(count, 1)
            float lv = (csum == 0.f) ? 0.f : (ssum / denom) * 0.2f;
            out[1 + j] = lv;
            total += lv;
        }
        out[0] = total;
    }
}

extern "C" void kernel_launch(void* const* d_in, const int* in_sizes, int n_in,
                              void* d_out, int out_size, void* d_ws, size_t ws_size,
                              hipStream_t stream) {
    const float* pre  = (const float*)d_in[0];
    const float* real = (const float*)d_in[1];
    float* out = (float*)d_out;
    int n = in_sizes[0];
    int n4 = n / 4;

    int blocks = (n4 + 511) / 512;                 // 8192 for N=16M
    if (blocks < 1) blocks = 1;

    // d_ws: 10 planes x nblocks floats (320 KB for 8192 blocks). Every slot
    // the final kernel reads is written by mcl_main first — the 0xAA poison
    // never flows into results, so NO memset node is needed.
    float* acc = (float*)d_ws;

    mcl_main<<<blocks, TPB, 0, stream>>>(pre, real, out + 6, acc, n4, n);
    mcl_final<<<1, 1024, 0, stream>>>(acc, out, blocks);
}

// Round 5
// 177.549 us; speedup vs baseline: 6.4307x; 1.0234x over previous
//
#include <hip/hip_runtime.h>

// MCLLoss: masked L1 loss over 5 overlapping value-ranges of real_img.
// Ranges: (-1,1), (-1,-.5), (-.5,0), (0,.5), (.5,1) — inclusive bounds,
// masks overlap; class_mask takes the LAST matching range index.
// Output layout: [loss, losses[5], class_mask_rescaled[N]]; rescale = cls*0.5-1.
//
// R10: attack the FINAL kernel's latency (main untouched — pinned at 63-64us
// across three shapes = empirical mixed read/write stream limit ~2.1 TB/s).
// Ledger fit across R5/R7/R8/R9: fixed per-call overhead C ~= 86us, so the
// separate final kernel has been costing ~25-30us. Cause: single cold block,
// scalar loads, ~10 outstanding misses against lines left dirty in 8
// non-coherent XCD L2s -> serialized ~1000cy round trips. Fix: float4
// plane-coalesced loads, 10 planes batched per iteration (40 independent
// 16B loads in flight per thread-pair of iterations), 1024 threads.
//  - Main = R5 shape: 8192 blocks x 2 float4-pairs, all loads upfront, plain
//    float2 mask stores, counts as floats (exact), plain-store SoA partials
//    (no atomics, no memset node, no fences — R8 showed fences cost 1ms).

#define TPB 256

__device__ __forceinline__ void proc_elem(float pv, float rv,
                                          float s[5], float c[5], float& ov)
{
    float d = fabsf(pv - rv);
    bool geM1  = rv >= -1.0f;
    bool leM05 = rv <= -0.5f;
    bool geM05 = rv >= -0.5f;
    bool le0   = rv <=  0.0f;
    bool ge0   = rv >=  0.0f;
    bool le05  = rv <=  0.5f;
    bool ge05  = rv >=  0.5f;
    bool le1   = rv <=  1.0f;
    bool in0 = geM1  && le1;
    bool in1 = geM1  && leM05;
    bool in2 = geM05 && le0;
    bool in3 = ge0   && le05;
    bool in4 = ge05  && le1;
    s[0] += in0 ? d : 0.f;  c[0] += in0 ? 1.f : 0.f;
    s[1] += in1 ? d : 0.f;  c[1] += in1 ? 1.f : 0.f;
    s[2] += in2 ? d : 0.f;  c[2] += in2 ? 1.f : 0.f;
    s[3] += in3 ? d : 0.f;  c[3] += in3 ? 1.f : 0.f;
    s[4] += in4 ? d : 0.f;  c[4] += in4 ? 1.f : 0.f;
    // class value directly as float: -1, -.5, 0, .5, 1 (last matching wins)
    ov = in4 ? 1.0f : (in3 ? 0.5f : (in2 ? 0.0f : (in1 ? -0.5f : -1.0f)));
}

__device__ __forceinline__ void proc_group(int i, const float4& p, const float4& r,
                                           float s[5], float c[5],
                                           float* __restrict__ mask_out)
{
    float ov0, ov1, ov2, ov3;
    proc_elem(p.x, r.x, s, c, ov0);
    proc_elem(p.y, r.y, s, c, ov1);
    proc_elem(p.z, r.z, s, c, ov2);
    proc_elem(p.w, r.w, s, c, ov3);
    // mask_out = out+6: 8-byte aligned only -> float2 stores
    float2* mo = (float2*)(mask_out + 4 * (size_t)i);
    mo[0] = make_float2(ov0, ov1);
    mo[1] = make_float2(ov2, ov3);
}

__global__ __launch_bounds__(TPB, 8) void mcl_main(
    const float* __restrict__ pre, const float* __restrict__ real,
    float* __restrict__ mask_out, float* __restrict__ acc, int n4, int n)
{
    float s[5] = {0.f, 0.f, 0.f, 0.f, 0.f};
    float c[5] = {0.f, 0.f, 0.f, 0.f, 0.f};

    const int t = threadIdx.x;
    const int i0 = blockIdx.x * 512 + t;   // block covers 512 float4 (8 KB)
    const int i1 = i0 + 256;
    const bool v0 = i0 < n4;
    const bool v1 = i1 < n4;

    const float4* pre4  = (const float4*)pre;
    const float4* real4 = (const float4*)real;

    // all four 16B loads upfront: one memory round-trip per thread, 64B in
    // flight for the block's whole life (R5 shape — proven fastest)
    float4 p0, r0, p1, r1;
    if (v0) { p0 = pre4[i0]; r0 = real4[i0]; }
    if (v1) { p1 = pre4[i1]; r1 = real4[i1]; }

    if (v0) proc_group(i0, p0, r0, s, c, mask_out);
    if (v1) proc_group(i1, p1, r1, s, c, mask_out);

    // scalar tail (n not divisible by 4)
    {
        int tail_base = n4 * 4;
        int tail = n - tail_base;
        int gtid = blockIdx.x * TPB + t;
        if (gtid < tail) {
            int idx = tail_base + gtid;
            float ov;
            proc_elem(pre[idx], real[idx], s, c, ov);
            mask_out[idx] = ov;
        }
    }

    // wave64 butterfly reduction (10 floats)
#pragma unroll
    for (int j = 0; j < 5; ++j) {
#pragma unroll
        for (int off = 32; off > 0; off >>= 1) {
            s[j] += __shfl_down(s[j], off, 64);
            c[j] += __shfl_down(c[j], off, 64);
        }
    }

    __shared__ float ls[4][5];
    __shared__ float lc[4][5];
    const int lane = t & 63;
    const int wave = t >> 6;
    if (lane == 0) {
#pragma unroll
        for (int j = 0; j < 5; ++j) { ls[wave][j] = s[j]; lc[wave][j] = c[j]; }
    }
    __syncthreads();

    // plain store of 10 partials into this block's private SoA slots.
    // No atomics, no zero-init dependency: final reads exactly what's written.
    if (t < 10) {
        int j = (t < 5) ? t : t - 5;
        float v = (t < 5) ? (ls[0][j] + ls[1][j] + ls[2][j] + ls[3][j])
                          : (lc[0][j] + lc[1][j] + lc[2][j] + lc[3][j]);
        acc[(size_t)t * gridDim.x + blockIdx.x] = v;
    }
}

__global__ __launch_bounds__(1024) void mcl_final(
    const float* __restrict__ acc, float* __restrict__ out, int nblocks)
{
    const int t = threadIdx.x;
    float sum[10];
#pragma unroll
    for (int j = 0; j < 10; ++j) sum[j] = 0.f;

    if ((nblocks & 3) == 0) {
        // vector path: plane j = nblocks contiguous floats, 16B-aligned.
        // Batch all 10 planes per iteration into independent float4 loads ->
        // 10 concurrent 16B requests/thread/iter (2 iters at nblocks=8192),
        // collapsing the serialized-miss chain of the scalar version.
        const int n4p = nblocks >> 2;
        for (int k4 = t; k4 < n4p; k4 += 1024) {
            float4 tmp[10];
#pragma unroll
            for (int j = 0; j < 10; ++j)
                tmp[j] = ((const float4*)(acc + (size_t)j * nblocks))[k4];
#pragma unroll
            for (int j = 0; j < 10; ++j)
                sum[j] += (tmp[j].x + tmp[j].y) + (tmp[j].z + tmp[j].w);
        }
    } else {
        for (int slot = t; slot < nblocks; slot += 1024) {
#pragma unroll
            for (int j = 0; j < 10; ++j)
                sum[j] += acc[(size_t)j * nblocks + slot];
        }
    }

    // wave butterfly
#pragma unroll
    for (int j = 0; j < 10; ++j) {
#pragma unroll
        for (int off = 32; off > 0; off >>= 1)
            sum[j] += __shfl_down(sum[j], off, 64);
    }

    __shared__ float fs[16][10];
    const int lane = t & 63;
    const int wave = t >> 6;
    if (lane == 0) {
#pragma unroll
        for (int j = 0; j < 10; ++j) fs[wave][j] = sum[j];
    }
    __syncthreads();

    __shared__ float red[10];
    if (t < 10) {
        float v = 0.f;
#pragma unroll
        for (int w = 0; w < 16; ++w) v += fs[w][t];
        red[t] = v;
    }
    __syncthreads();

    if (t == 0) {
        float total = 0.f;
#pragma unroll
        for (int j = 0; j < 5; ++j) {
            float ssum = red[j];
            float csum = red[5 + j];                  // exact integer-valued float
            float denom = csum > 1.f ? csum : 1.f;    // max(count, 1)
            float lv = (csum == 0.f) ? 0.f : (ssum / denom) * 0.2f;
            out[1 + j] = lv;
            total += lv;
        }
        out[0] = total;
    }
}

extern "C" void kernel_launch(void* const* d_in, const int* in_sizes, int n_in,
                              void* d_out, int out_size, void* d_ws, size_t ws_size,
                              hipStream_t stream) {
    const float* pre  = (const float*)d_in[0];
    const float* real = (const float*)d_in[1];
    float* out = (float*)d_out;
    int n = in_sizes[0];
    int n4 = n / 4;

    int blocks = (n4 + 511) / 512;                 // 8192 for N=16M
    if (blocks < 1) blocks = 1;

    // d_ws: 10 planes x nblocks floats (320 KB for 8192 blocks). Every slot
    // the final kernel reads is written by mcl_main first — the 0xAA poison
    // never flows into results, so NO memset node is needed.
    float* acc = (float*)d_ws;

    mcl_main<<<blocks, TPB, 0, stream>>>(pre, real, out + 6, acc, n4, n);
    mcl_final<<<1, 1024, 0, stream>>>(acc, out, blocks);
}